// Round 1
// baseline (262.845 us; speedup 1.0000x reference)
//
#include <hip/hip_runtime.h>

// Gaussian RBF splatting: out[q,c] = sum_n exp(-50*r2(q,n))*d_val[n,c] / (1e-4 + sum_n exp(-50*r2(q,n)))
// Q=16384 queries, N=8192 data points, C=64 channels, all float32.

#define QQ 16384
#define NN 8192
#define CC 64

// ---- partial kernel: each lane = one query, all lanes walk the same n ----
// d_pos[n] / d_val[n][*] addresses are wave-uniform -> scalar loads (K$ broadcast).
// Partials stored as ws_val[(s*CC + c)*Q + q] (coalesced store & reduce read).
__global__ __launch_bounds__(256)
void splat_partial(const float* __restrict__ q_pos,
                   const float* __restrict__ d_pos,
                   const float* __restrict__ d_val,
                   float* __restrict__ ws_val,
                   float* __restrict__ ws_w,
                   int Q, int n_per_slice)
{
    const int q = blockIdx.x * blockDim.x + threadIdx.x;
    const int s = blockIdx.y;
    const int n0 = s * n_per_slice;

    const float qx = q_pos[q * 3 + 0];
    const float qy = q_pos[q * 3 + 1];
    const float qz = q_pos[q * 3 + 2];

    float acc[CC];
#pragma unroll
    for (int c = 0; c < CC; ++c) acc[c] = 0.0f;
    float wsum = 0.0f;

    for (int n = n0; n < n0 + n_per_slice; ++n) {
        const float px = d_pos[n * 3 + 0];
        const float py = d_pos[n * 3 + 1];
        const float pz = d_pos[n * 3 + 2];
        const float dx = qx - px;
        const float dy = qy - py;
        const float dz = qz - pz;
        const float r2 = fmaf(dx, dx, fmaf(dy, dy, dz * dz));
        const float w  = __expf(-50.0f * r2);
        wsum += w;

        const float4* __restrict__ row4 =
            reinterpret_cast<const float4*>(d_val + (size_t)n * CC);
#pragma unroll
        for (int j = 0; j < CC / 4; ++j) {
            const float4 v = row4[j];   // wave-uniform -> s_load_dwordx4
            acc[4 * j + 0] = fmaf(w, v.x, acc[4 * j + 0]);
            acc[4 * j + 1] = fmaf(w, v.y, acc[4 * j + 1]);
            acc[4 * j + 2] = fmaf(w, v.z, acc[4 * j + 2]);
            acc[4 * j + 3] = fmaf(w, v.w, acc[4 * j + 3]);
        }
    }

#pragma unroll
    for (int c = 0; c < CC; ++c)
        ws_val[((size_t)s * CC + c) * Q + q] = acc[c];   // coalesced (q fastest)
    ws_w[(size_t)s * Q + q] = wsum;
}

// ---- reduce + normalize: blockIdx.y = channel, x covers queries ----
__global__ __launch_bounds__(256)
void splat_reduce(const float* __restrict__ ws_val,
                  const float* __restrict__ ws_w,
                  float* __restrict__ out,
                  int Q, int nslice)
{
    const int q = blockIdx.x * blockDim.x + threadIdx.x;
    const int c = blockIdx.y;
    float v = 0.0f;
    for (int s = 0; s < nslice; ++s)
        v += ws_val[((size_t)s * CC + c) * Q + q];       // coalesced
    float wsum = 0.0f;
    for (int s = 0; s < nslice; ++s)
        wsum += ws_w[(size_t)s * Q + q];                 // coalesced
    out[(size_t)q * CC + c] = v / (1e-4f + wsum);        // merged in L2
}

// ---- fallback: single pass, direct normalized write (no workspace) ----
__global__ __launch_bounds__(256)
void splat_direct(const float* __restrict__ q_pos,
                  const float* __restrict__ d_pos,
                  const float* __restrict__ d_val,
                  float* __restrict__ out,
                  int Q, int N)
{
    const int q = blockIdx.x * blockDim.x + threadIdx.x;
    const float qx = q_pos[q * 3 + 0];
    const float qy = q_pos[q * 3 + 1];
    const float qz = q_pos[q * 3 + 2];

    float acc[CC];
#pragma unroll
    for (int c = 0; c < CC; ++c) acc[c] = 0.0f;
    float wsum = 0.0f;

    for (int n = 0; n < N; ++n) {
        const float px = d_pos[n * 3 + 0];
        const float py = d_pos[n * 3 + 1];
        const float pz = d_pos[n * 3 + 2];
        const float dx = qx - px;
        const float dy = qy - py;
        const float dz = qz - pz;
        const float r2 = fmaf(dx, dx, fmaf(dy, dy, dz * dz));
        const float w  = __expf(-50.0f * r2);
        wsum += w;
        const float4* __restrict__ row4 =
            reinterpret_cast<const float4*>(d_val + (size_t)n * CC);
#pragma unroll
        for (int j = 0; j < CC / 4; ++j) {
            const float4 v = row4[j];
            acc[4 * j + 0] = fmaf(w, v.x, acc[4 * j + 0]);
            acc[4 * j + 1] = fmaf(w, v.y, acc[4 * j + 1]);
            acc[4 * j + 2] = fmaf(w, v.z, acc[4 * j + 2]);
            acc[4 * j + 3] = fmaf(w, v.w, acc[4 * j + 3]);
        }
    }
    const float inv = 1.0f / (1e-4f + wsum);
#pragma unroll
    for (int c = 0; c < CC; ++c)
        out[(size_t)q * CC + c] = acc[c] * inv;
}

extern "C" void kernel_launch(void* const* d_in, const int* in_sizes, int n_in,
                              void* d_out, int out_size, void* d_ws, size_t ws_size,
                              hipStream_t stream) {
    const float* q_pos = (const float*)d_in[0];
    const float* d_pos = (const float*)d_in[1];
    const float* d_val = (const float*)d_in[2];
    float* out = (float*)d_out;

    const int Q = in_sizes[0] / 3;   // 16384
    const int N = in_sizes[1] / 3;   // 8192

    // choose slice count (power of 2, <=16) that fits the workspace
    int ns = 16;
    while (ns > 1 && (size_t)ns * Q * (CC + 1) * sizeof(float) > ws_size) ns >>= 1;

    if ((size_t)ns * Q * (CC + 1) * sizeof(float) > ws_size || ns < 2) {
        // workspace too small: direct single-pass (correct, lower occupancy)
        splat_direct<<<dim3(Q / 256), dim3(256), 0, stream>>>(
            q_pos, d_pos, d_val, out, Q, N);
        return;
    }

    float* ws_val = (float*)d_ws;                       // ns*CC*Q floats
    float* ws_w   = ws_val + (size_t)ns * CC * Q;       // ns*Q floats

    dim3 grid1(Q / 256, ns);
    splat_partial<<<grid1, dim3(256), 0, stream>>>(
        q_pos, d_pos, d_val, ws_val, ws_w, Q, N / ns);

    dim3 grid2(Q / 256, CC);
    splat_reduce<<<grid2, dim3(256), 0, stream>>>(ws_val, ws_w, out, Q, ns);
}

// Round 2
// 113.229 us; speedup vs baseline: 2.3214x; 2.3214x over previous
//
#include <hip/hip_runtime.h>
#include <hip/hip_bf16.h>

// out[q,c] = sum_n exp(-50*r2(q,n)) * d_val[n,c] / (1e-4 + sum_n exp(-50*r2(q,n)))
// Q=16384, N=8192, C=64, f32 in/out.
// MFMA formulation: W (generated bf16) @ V (bf16), f32 accumulate.

#define QTOT 16384
#define NTOT 8192
#define CCH  64

typedef __attribute__((ext_vector_type(8))) short bf16x8;
typedef __attribute__((ext_vector_type(4))) float f32x4;
typedef __attribute__((ext_vector_type(4))) int   i32x4;

// exp(-50 r^2) = exp2( q . p' + A_q + B_n ), p' = 144.2695*p, B_n = -72.13474*|p|^2
#define K2F 144.269504089f
#define K1F 72.1347520444f

// ---------- prep: P4[n] = {K2*px, K2*py, K2*pz, -K1*|p|^2} ----------
__global__ __launch_bounds__(256)
void prep_p4(const float* __restrict__ dp, float4* __restrict__ P4) {
    int n = blockIdx.x * 256 + threadIdx.x;
    if (n >= NTOT) return;
    float px = dp[3 * n + 0], py = dp[3 * n + 1], pz = dp[3 * n + 2];
    float4 r;
    r.x = K2F * px; r.y = K2F * py; r.z = K2F * pz;
    r.w = -K1F * (px * px + py * py + pz * pz);
    P4[n] = r;
}

// ---------- prep: Vt[c][n] = bf16(d_val[n][c]) (transposed, bf16) ----------
__global__ __launch_bounds__(256)
void prep_vt(const float* __restrict__ dv, __hip_bfloat16* __restrict__ Vt) {
    int t = blockIdx.x * 256 + threadIdx.x;   // t = c*NTOT + n
    int c = t >> 13;                          // NTOT = 8192
    int n = t & (NTOT - 1);
    Vt[t] = __float2bfloat16(dv[n * CCH + c]);  // coalesced write, L2-absorbed read
}

// ---------- main: per wave 32q x 64c, loop n-slice in steps of 32 ----------
__global__ __launch_bounds__(256)
void splat_mfma(const float* __restrict__ q_pos,
                const float4* __restrict__ P4,
                const __hip_bfloat16* __restrict__ Vt,   // [64][NTOT]
                float* __restrict__ ws_val,              // [NS][QTOT][64]
                float* __restrict__ ws_w,                // [NS][QTOT]
                int npers)                               // n per slice (mult of 32)
{
    const int wave = threadIdx.x >> 6;
    const int lane = threadIdx.x & 63;
    const int r    = lane & 15;     // A row / B col / C col index
    const int hi   = lane >> 4;     // k-group
    const int qbase = blockIdx.x * 128 + wave * 32;
    const int s  = blockIdx.y;
    const int n0 = s * npers;

    // per-lane q data for the two 16-q tiles
    float qx[2], qy[2], qz[2], Aq[2];
#pragma unroll
    for (int t = 0; t < 2; ++t) {
        int q = qbase + t * 16 + r;
        float x = q_pos[3 * q + 0], y = q_pos[3 * q + 1], z = q_pos[3 * q + 2];
        qx[t] = x; qy[t] = y; qz[t] = z;
        Aq[t] = -K1F * (x * x + y * y + z * z);
    }

    f32x4 acc[2][4];
#pragma unroll
    for (int t = 0; t < 2; ++t)
#pragma unroll
        for (int cg = 0; cg < 4; ++cg)
            acc[t][cg] = (f32x4)(0.0f);
    float wsum[2] = {0.0f, 0.0f};

    for (int nb = n0; nb < n0 + npers; nb += 32) {
        // P4 for this lane's 8 n values (16 lanes per hi-group share -> broadcast loads)
        float4 p4[8];
        const float4* pp = P4 + nb + 8 * hi;
#pragma unroll
        for (int b = 0; b < 8; ++b) p4[b] = pp[b];

        // B fragments: lane holds V[nb+8*hi+b][cg*16+r] = Vt[cg*16+r][nb+8*hi+b], 8 contiguous
        union BF { i32x4 i; bf16x8 v; } bfr[4];
#pragma unroll
        for (int cg = 0; cg < 4; ++cg) {
            const i32x4* bp = (const i32x4*)(Vt + (size_t)(cg * 16 + r) * NTOT + nb + 8 * hi);
            bfr[cg].i = *bp;
        }

        // A fragments: lane holds W[qbase+t*16+r][k=8*hi+b]
        union AF { unsigned u[4]; bf16x8 v; } af[2];
#pragma unroll
        for (int t = 0; t < 2; ++t) {
            float w[8];
#pragma unroll
            for (int b = 0; b < 8; ++b) {
                float bias = p4[b].w + Aq[t];
                float arg = fmaf(qz[t], p4[b].z, fmaf(qy[t], p4[b].y, fmaf(qx[t], p4[b].x, bias)));
                w[b] = __builtin_amdgcn_exp2f(arg);
                wsum[t] += w[b];
            }
#pragma unroll
            for (int d = 0; d < 4; ++d) {
                unsigned u;
                asm("v_cvt_pk_bf16_f32 %0, %1, %2" : "=v"(u) : "v"(w[2 * d]), "v"(w[2 * d + 1]));
                af[t].u[d] = u;
            }
        }

#pragma unroll
        for (int t = 0; t < 2; ++t)
#pragma unroll
            for (int cg = 0; cg < 4; ++cg)
                acc[t][cg] = __builtin_amdgcn_mfma_f32_16x16x32_bf16(af[t].v, bfr[cg].v, acc[t][cg], 0, 0, 0);
    }

    // wsum: lanes with same r hold disjoint n-subsets of the same q -> reduce over hi
#pragma unroll
    for (int t = 0; t < 2; ++t) {
        float wv = wsum[t];
        wv += __shfl_xor(wv, 16);
        wv += __shfl_xor(wv, 32);
        wsum[t] = wv;
    }

    // C layout (verified m89): col = lane&15 (channel), row = 4*hi + j (q offset)
    float* wsv = ws_val + (size_t)s * QTOT * CCH;
#pragma unroll
    for (int t = 0; t < 2; ++t) {
#pragma unroll
        for (int cg = 0; cg < 4; ++cg)
#pragma unroll
            for (int j = 0; j < 4; ++j) {
                int q = qbase + t * 16 + 4 * hi + j;
                int c = cg * 16 + r;
                wsv[(size_t)q * CCH + c] = acc[t][cg][j];
            }
        if (lane < 16)
            ws_w[(size_t)s * QTOT + qbase + t * 16 + lane] = wsum[t];
    }
}

// ---------- reduce + normalize ----------
__global__ __launch_bounds__(256)
void splat_reduce2(const float* __restrict__ ws_val,
                   const float* __restrict__ ws_w,
                   float* __restrict__ out, int NS) {
    int t = blockIdx.x * 256 + threadIdx.x;   // t = q*64 + c
    int q = t >> 6;
    float v = 0.0f, wsum = 0.0f;
    for (int s = 0; s < NS; ++s) {
        v    += ws_val[(size_t)s * QTOT * CCH + t];
        wsum += ws_w[(size_t)s * QTOT + q];
    }
    out[t] = v / (1e-4f + wsum);
}

// ---------- fallback: single pass VALU (round-0 kernel) ----------
__global__ __launch_bounds__(256)
void splat_direct(const float* __restrict__ q_pos,
                  const float* __restrict__ d_pos,
                  const float* __restrict__ d_val,
                  float* __restrict__ out, int Q, int N)
{
    const int q = blockIdx.x * blockDim.x + threadIdx.x;
    const float qx = q_pos[q * 3 + 0], qy = q_pos[q * 3 + 1], qz = q_pos[q * 3 + 2];
    float acc[CCH];
#pragma unroll
    for (int c = 0; c < CCH; ++c) acc[c] = 0.0f;
    float wsum = 0.0f;
    for (int n = 0; n < N; ++n) {
        float dx = qx - d_pos[n * 3 + 0];
        float dy = qy - d_pos[n * 3 + 1];
        float dz = qz - d_pos[n * 3 + 2];
        float r2 = fmaf(dx, dx, fmaf(dy, dy, dz * dz));
        float w = __expf(-50.0f * r2);
        wsum += w;
        const float4* row4 = reinterpret_cast<const float4*>(d_val + (size_t)n * CCH);
#pragma unroll
        for (int j = 0; j < CCH / 4; ++j) {
            float4 v = row4[j];
            acc[4 * j + 0] = fmaf(w, v.x, acc[4 * j + 0]);
            acc[4 * j + 1] = fmaf(w, v.y, acc[4 * j + 1]);
            acc[4 * j + 2] = fmaf(w, v.z, acc[4 * j + 2]);
            acc[4 * j + 3] = fmaf(w, v.w, acc[4 * j + 3]);
        }
    }
    float inv = 1.0f / (1e-4f + wsum);
#pragma unroll
    for (int c = 0; c < CCH; ++c) out[(size_t)q * CCH + c] = acc[c] * inv;
}

extern "C" void kernel_launch(void* const* d_in, const int* in_sizes, int n_in,
                              void* d_out, int out_size, void* d_ws, size_t ws_size,
                              hipStream_t stream) {
    const float* q_pos = (const float*)d_in[0];
    const float* d_pos = (const float*)d_in[1];
    const float* d_val = (const float*)d_in[2];
    float* out = (float*)d_out;

    const size_t p4_bytes = (size_t)NTOT * 16;              // 128 KiB
    const size_t vt_bytes = (size_t)NTOT * CCH * 2;         // 1 MiB

    int NS = 8;
    while (NS >= 1) {
        size_t need = p4_bytes + vt_bytes
                    + (size_t)NS * QTOT * CCH * 4 + (size_t)NS * QTOT * 4;
        if (need <= ws_size) break;
        NS >>= 1;
    }
    if (NS < 1) {
        splat_direct<<<dim3(QTOT / 256), dim3(256), 0, stream>>>(
            q_pos, d_pos, d_val, out, QTOT, NTOT);
        return;
    }

    float4*          P4 = (float4*)d_ws;
    __hip_bfloat16*  Vt = (__hip_bfloat16*)((char*)d_ws + p4_bytes);
    float*       ws_valp = (float*)((char*)d_ws + p4_bytes + vt_bytes);
    float*         ws_wp = ws_valp + (size_t)NS * QTOT * CCH;

    prep_p4<<<dim3(NTOT / 256), dim3(256), 0, stream>>>(d_pos, P4);
    prep_vt<<<dim3(NTOT * CCH / 256), dim3(256), 0, stream>>>(d_val, Vt);

    splat_mfma<<<dim3(QTOT / 128, NS), dim3(256), 0, stream>>>(
        q_pos, P4, Vt, ws_valp, ws_wp, NTOT / NS);

    splat_reduce2<<<dim3(QTOT * CCH / 256), dim3(256), 0, stream>>>(
        ws_valp, ws_wp, out, NS);
}